// Round 8
// baseline (5102.259 us; speedup 1.0000x reference)
//
#include <hip/hip_runtime.h>
#include <hip/hip_bf16.h>
#include <cstdint>
#include <cstddef>

typedef __bf16 bf16;
typedef bf16 bf16x8 __attribute__((ext_vector_type(8)));
typedef float f32x4 __attribute__((ext_vector_type(4)));

#define D_DIM 128
#define EB 32      // edges per tile
#define T_TILES 16 // tiles per block (edge kernel)
#define TS 136     // LDS stride for 128-wide bf16 tiles (+8 pad)
#define XS 264     // LDS stride for 256-wide x2 bf16 tile
#define SRS 132    // LDS stride for 128-wide f32 sred tile (aliased over x2)
#define AS 392     // LDS stride for 384-wide node-A input tile

__device__ __forceinline__ f32x4 mfma16(bf16x8 a, bf16x8 b, f32x4 c) {
  return __builtin_amdgcn_mfma_f32_16x16x32_bf16(a, b, c, 0, 0, 0);
}

__device__ __forceinline__ int clampi(int v, int hi) {
  return v < 0 ? 0 : (v > hi ? hi : v);
}

// stage 16 consecutive f32 (64B, aligned) -> 16 bf16 in LDS
__device__ __forceinline__ void stage16(const float* __restrict__ src, bf16* dst) {
  bf16 tmp[16];
#pragma unroll
  for (int q = 0; q < 4; ++q) {
    f32x4 f = ((const f32x4*)src)[q];
#pragma unroll
    for (int j = 0; j < 4; ++j) tmp[q * 4 + j] = (bf16)f[j];
  }
  *(bf16x8*)dst = *(bf16x8*)tmp;
  *(bf16x8*)(dst + 8) = *(bf16x8*)(tmp + 8);
}

// ---- layer1: A[32 x K] @ W1t[256 x K]^T, relu(+b1) -> x2[32 x 256] bf16
template <int NSEG>
__device__ __forceinline__ void mlp_layer1(const bf16* s0, const bf16* s1, const bf16* s2,
                                           const int S,
                                           const bf16* __restrict__ W1t,
                                           const float* __restrict__ B1,
                                           bf16* x2, const int lane, const int w) {
  const int col = lane & 15, quad = lane >> 4;
  const int K = NSEG * 128;
  f32x4 acc[2][4] = {};
  const bf16* segs[3] = {s0, s1, s2};
#pragma unroll
  for (int sg = 0; sg < NSEG; ++sg) {
    const bf16* xl = segs[sg];
#pragma unroll
    for (int kk = 0; kk < 128; kk += 32) {
      const int k0 = sg * 128 + kk;
      bf16x8 a0 = *(const bf16x8*)&xl[col * S + kk + quad * 8];
      bf16x8 a1 = *(const bf16x8*)&xl[(col + 16) * S + kk + quad * 8];
#pragma unroll
      for (int nt = 0; nt < 4; ++nt) {
        bf16x8 b = *(const bf16x8*)(W1t + (size_t)(w * 64 + nt * 16 + col) * K + k0 + quad * 8);
        acc[0][nt] = mfma16(a0, b, acc[0][nt]);
        acc[1][nt] = mfma16(a1, b, acc[1][nt]);
      }
    }
  }
#pragma unroll
  for (int nt = 0; nt < 4; ++nt) {
    const int n = w * 64 + nt * 16 + col;
    const float b1 = B1[n];
#pragma unroll
    for (int mt = 0; mt < 2; ++mt)
#pragma unroll
      for (int i = 0; i < 4; ++i) {
        float v = acc[mt][nt][i] + b1;
        x2[(mt * 16 + quad * 4 + i) * XS + n] = (bf16)(v > 0.f ? v : 0.f);
      }
  }
}

// ---- layer2: x2[32 x 256] @ W2t[128 x 256]^T -> acc2
__device__ __forceinline__ void mlp_layer2(const bf16* x2, const bf16* __restrict__ W2t,
                                           const int lane, const int w, f32x4 acc2[2][2]) {
  const int col = lane & 15, quad = lane >> 4;
#pragma unroll
  for (int k0 = 0; k0 < 256; k0 += 32) {
    bf16x8 a0 = *(const bf16x8*)&x2[col * XS + k0 + quad * 8];
    bf16x8 a1 = *(const bf16x8*)&x2[(col + 16) * XS + k0 + quad * 8];
#pragma unroll
    for (int nt = 0; nt < 2; ++nt) {
      bf16x8 b = *(const bf16x8*)(W2t + (size_t)(w * 32 + nt * 16 + col) * 256 + k0 + quad * 8);
      acc2[0][nt] = mfma16(a0, b, acc2[0][nt]);
      acc2[1][nt] = mfma16(a1, b, acc2[1][nt]);
    }
  }
}

// ---------------- small utility kernels ----------------

// f32 [K,N] -> bf16 [N,K]
__global__ void transpose_kernel(const float* __restrict__ in, bf16* __restrict__ out,
                                 int K, int N) {
  int k = blockIdx.x * blockDim.x + threadIdx.x;
  int n = blockIdx.y;
  if (k < K) out[(size_t)n * K + k] = (bf16)in[(size_t)k * N + n];
}

__global__ void count_kernel(const int* __restrict__ epn, const int* __restrict__ ecn,
                             int* cntp, int* cntc, int E, int N) {
  int i = blockIdx.x * blockDim.x + threadIdx.x;
  if (i < E) {
    atomicAdd(&cntp[clampi(epn[i], N - 1)], 1);
    atomicAdd(&cntc[clampi(ecn[i], N - 1)], 1);
  }
}

__global__ void inv_kernel(const int* __restrict__ cntp, const int* __restrict__ cntc,
                           float* invp, float* invc, int N) {
  int i = blockIdx.x * blockDim.x + threadIdx.x;
  if (i < N) {
    invp[i] = 1.f / fmaxf((float)cntp[i], 1.f);
    invc[i] = 1.f / fmaxf((float)cntc[i], 1.f);
  }
}

// single-block exclusive scan of cnt[n] -> offs[n]
__global__ void scan_kernel(const int* __restrict__ cnt, int* __restrict__ offs, int n) {
  __shared__ int buf[1024];
  __shared__ int carry;
  const int t = threadIdx.x;
  if (t == 0) carry = 0;
  __syncthreads();
  for (int base = 0; base < n; base += 1024) {
    int v = (base + t < n) ? cnt[base + t] : 0;
    buf[t] = v;
    __syncthreads();
    for (int d = 1; d < 1024; d <<= 1) {
      int add = (t >= d) ? buf[t - d] : 0;
      __syncthreads();
      buf[t] += add;
      __syncthreads();
    }
    if (base + t < n) offs[base + t] = carry + buf[t] - v;  // exclusive
    __syncthreads();
    if (t == 1023) carry += buf[1023];
    __syncthreads();
  }
}

// counting-sort scatter: edge ids grouped by destination node
__global__ void scatter_kernel(const int* __restrict__ epn, const int* __restrict__ ecn,
                               const int* __restrict__ offp, const int* __restrict__ offc,
                               int* curp, int* curc, int* sortp, int* sortc, int E, int N) {
  int i = blockIdx.x * blockDim.x + threadIdx.x;
  if (i < E) {
    int p = clampi(epn[i], N - 1);
    sortp[offp[p] + atomicAdd(&curp[p], 1)] = i;
    int c = clampi(ecn[i], N - 1);
    sortc[offc[c] + atomicAdd(&curc[c], 1)] = i;
  }
}

// ---------------- MLP_V: h = mlp(batch_token), h stored f32 + bf16 copy ----------------

__global__ __launch_bounds__(256, 2) void node_v_kernel(
    const float* __restrict__ bt, const bf16* __restrict__ W1t, const float* __restrict__ B1,
    const bf16* __restrict__ W2t, const float* __restrict__ B2,
    float* __restrict__ hout, bf16* __restrict__ hbf, int N) {
  __shared__ __attribute__((aligned(16))) bf16 x[EB * TS];
  __shared__ __attribute__((aligned(16))) bf16 x2[EB * XS];
  const int t = threadIdx.x;
  const int r0 = blockIdx.x * EB;
  {
    const int r = t >> 3, c0 = (t & 7) * 16;
    int g = r0 + r; if (g >= N) g = N - 1;
    stage16(bt + (size_t)g * D_DIM + c0, &x[r * TS + c0]);
  }
  __syncthreads();
  const int lane = t & 63, w = t >> 6, col = lane & 15, quad = lane >> 4;
  mlp_layer1<1>(x, x, x, TS, W1t, B1, x2, lane, w);
  __syncthreads();
  f32x4 acc2[2][2] = {};
  mlp_layer2(x2, W2t, lane, w, acc2);
#pragma unroll
  for (int nt = 0; nt < 2; ++nt) {
    const int n = w * 32 + nt * 16 + col;
    const float b2 = B2[n];
#pragma unroll
    for (int mt = 0; mt < 2; ++mt)
#pragma unroll
      for (int i = 0; i < 4; ++i) {
        int m = mt * 16 + quad * 4 + i;
        int g = r0 + m;
        if (g < N) {
          float v = acc2[mt][nt][i] + b2;
          v = v > 0.f ? v : 0.f;
          hout[(size_t)g * D_DIM + n] = v;
          hbf[(size_t)g * D_DIM + n] = (bf16)v;
        }
      }
  }
}

// ---------------- per-hop edge kernel: persistent tiles + prefetch pipeline ----------------
// side 0 (P): s_p = MLP_P([hc, hp, ep]) summed by epn -> accp
// side 1 (C): s_c = MLP_C([hp, hc, ec]) summed by ecn -> accc

__global__ __launch_bounds__(256, 3) void edge_side_kernel(
    const bf16* __restrict__ hbf,
    const float* __restrict__ epi, const float* __restrict__ eci,
    const int* __restrict__ epn, const int* __restrict__ ecn,
    const int* __restrict__ sortp, const int* __restrict__ sortc,
    const float* __restrict__ Ew1, const float* __restrict__ Eb1,
    const bf16* __restrict__ Ew2t, const float* __restrict__ Eb2,
    const bf16* __restrict__ Pw1t, const float* __restrict__ Pb1,
    const bf16* __restrict__ Pw2t, const float* __restrict__ Pb2,
    const bf16* __restrict__ Cw1t, const float* __restrict__ Cb1,
    const bf16* __restrict__ Cw2t, const float* __restrict__ Cb2,
    float* __restrict__ accp, float* __restrict__ accc, int E, int N) {
  const int side = blockIdx.y;  // wave-uniform
  const float* ei    = side ? eci : epi;
  const int* own_n   = side ? ecn : epn;
  const int* oth_n   = side ? epn : ecn;
  const int* sorted  = side ? sortc : sortp;
  const bf16* W1t    = side ? Cw1t : Pw1t;
  const float* B1    = side ? Cb1 : Pb1;
  const bf16* W2t    = side ? Cw2t : Pw2t;
  const float* B2    = side ? Cb2 : Pb2;
  float* acc         = side ? accc : accp;

  __shared__ int s_own[T_TILES * EB];   // doubles as segment key; -1 = pad
  __shared__ int s_oth[T_TILES * EB];
  __shared__ float s_x[T_TILES * EB];
  __shared__ float s_ew1[256], s_eb1[256];
  __shared__ __attribute__((aligned(16))) bf16 tiles[3 * EB * TS];  // h_oth, h_own, feat
  __shared__ __attribute__((aligned(16))) char xbuf[EB * XS * 2];   // x2 bf16 / sred f32
  bf16* x2 = (bf16*)xbuf;
  float* sred = (float*)xbuf;

  const int t = threadIdx.x;
  const int ebase = blockIdx.x * (T_TILES * EB);
  // bulk index load for all tiles of this block
  for (int i = t; i < T_TILES * EB; i += 256) {
    int e = ebase + i;
    if (e < E) {
      int id = clampi(sorted[e], E - 1);
      s_own[i] = clampi(own_n[id], N - 1);
      s_oth[i] = clampi(oth_n[id], N - 1);
      s_x[i] = ei[id];
    } else {
      s_own[i] = -1; s_oth[i] = 0; s_x[i] = 0.f;
    }
  }
  s_ew1[t] = Ew1[t];
  s_eb1[t] = Eb1[t];
  __syncthreads();

  const int lane = t & 63, w = t >> 6, col = lane & 15, quad = lane >> 4;
  const int pr = t >> 3, pc = (t & 7) * 16;  // prefetch: row, col-chunk (16 bf16)
  const float eb2n0 = Eb2[w * 32 + col];
  const float eb2n1 = Eb2[w * 32 + 16 + col];

  bf16x8 pf_ot0, pf_ot1, pf_ow0, pf_ow1;
  auto prefetch = [&](int j) {
    int r = j * EB + pr;
    int ro = s_own[r]; if (ro < 0) ro = 0;
    int rt = s_oth[r];
    const bf16* po = hbf + (size_t)ro * D_DIM + pc;
    const bf16* pt = hbf + (size_t)rt * D_DIM + pc;
    pf_ow0 = *(const bf16x8*)po; pf_ow1 = *(const bf16x8*)(po + 8);
    pf_ot0 = *(const bf16x8*)pt; pf_ot1 = *(const bf16x8*)(pt + 8);
  };
  prefetch(0);

  for (int it = 0; it < T_TILES; ++it) {
    // ---- stage 1: write h tiles from prefetched regs; featgen in regs -> feat tile
    *(bf16x8*)&tiles[0 * EB * TS + pr * TS + pc] = pf_ot0;
    *(bf16x8*)&tiles[0 * EB * TS + pr * TS + pc + 8] = pf_ot1;
    *(bf16x8*)&tiles[1 * EB * TS + pr * TS + pc] = pf_ow0;
    *(bf16x8*)&tiles[1 * EB * TS + pr * TS + pc + 8] = pf_ow1;
    {
      const float xv0 = s_x[it * EB + col];
      const float xv1 = s_x[it * EB + col + 16];
      f32x4 fa[2][2] = {};
#pragma unroll
      for (int k0 = 0; k0 < 256; k0 += 32) {
        const int kb = k0 + quad * 8;
        f32x4 e0 = *(const f32x4*)&s_ew1[kb];
        f32x4 e1 = *(const f32x4*)&s_ew1[kb + 4];
        f32x4 b0 = *(const f32x4*)&s_eb1[kb];
        f32x4 b1 = *(const f32x4*)&s_eb1[kb + 4];
        bf16 a0v[8], a1v[8];
#pragma unroll
        for (int j = 0; j < 4; ++j) {
          float v;
          v = xv0 * e0[j] + b0[j]; a0v[j]     = (bf16)(v > 0.f ? v : 0.f);
          v = xv0 * e1[j] + b1[j]; a0v[4 + j] = (bf16)(v > 0.f ? v : 0.f);
          v = xv1 * e0[j] + b0[j]; a1v[j]     = (bf16)(v > 0.f ? v : 0.f);
          v = xv1 * e1[j] + b1[j]; a1v[4 + j] = (bf16)(v > 0.f ? v : 0.f);
        }
        bf16x8 a0 = *(bf16x8*)a0v, a1 = *(bf16x8*)a1v;
#pragma unroll
        for (int nt = 0; nt < 2; ++nt) {
          bf16x8 b = *(const bf16x8*)(Ew2t + (size_t)(w * 32 + nt * 16 + col) * 256 + k0 + quad * 8);
          fa[0][nt] = mfma16(a0, b, fa[0][nt]);
          fa[1][nt] = mfma16(a1, b, fa[1][nt]);
        }
      }
      bf16* dst = &tiles[2 * EB * TS];
#pragma unroll
      for (int nt = 0; nt < 2; ++nt) {
        const int n = w * 32 + nt * 16 + col;
        const float b2 = nt ? eb2n1 : eb2n0;
#pragma unroll
        for (int mt = 0; mt < 2; ++mt)
#pragma unroll
          for (int i = 0; i < 4; ++i) {
            float v = fa[mt][nt][i] + b2;
            dst[(mt * 16 + quad * 4 + i) * TS + n] = (bf16)(v > 0.f ? v : 0.f);
          }
      }
    }
    __syncthreads();  // A: all tiles visible
    // ---- issue gathers for next tile (consumed next iteration)
    if (it + 1 < T_TILES) prefetch(it + 1);
    // ---- main MLP
    mlp_layer1<3>(&tiles[0], &tiles[EB * TS], &tiles[2 * EB * TS], TS, W1t, B1, x2, lane, w);
    __syncthreads();  // B: x2 visible
    f32x4 acc2[2][2] = {};
    mlp_layer2(x2, W2t, lane, w, acc2);
    __syncthreads();  // C: x2 reads done (sred aliases x2)
    // ---- sred write + wave-private segmented reduce (wave w owns cols w*32..+31)
#pragma unroll
    for (int nt = 0; nt < 2; ++nt) {
      const int n = w * 32 + nt * 16 + col;
      const float b2 = B2[n];
#pragma unroll
      for (int mt = 0; mt < 2; ++mt)
#pragma unroll
        for (int i = 0; i < 4; ++i) {
          float v = acc2[mt][nt][i] + b2;
          sred[(mt * 16 + quad * 4 + i) * SRS + n] = v > 0.f ? v : 0.f;
        }
    }
    {
      const int c = w * 32 + (lane >> 1);
      const int rlo = (lane & 1) * 16;
      const int kb = it * EB;
      float run = 0.f;
      int cur = s_own[kb + rlo];
      for (int r = rlo; r < rlo + 16; ++r) {
        int k = s_own[kb + r];
        if (k != cur) {
          if (cur >= 0)
            __hip_atomic_fetch_add(&acc[(size_t)cur * D_DIM + c], run,
                                   __ATOMIC_RELAXED, __HIP_MEMORY_SCOPE_AGENT);
          run = 0.f;
          cur = k;
        }
        run += sred[r * SRS + c];
      }
      if (cur >= 0)
        __hip_atomic_fetch_add(&acc[(size_t)cur * D_DIM + c], run,
                               __ATOMIC_RELAXED, __HIP_MEMORY_SCOPE_AGENT);
    }
    // next iter's barrier A orders segreduce before x2/sred clobber
  }
}

// ---------------- per-hop node kernel: MLP_A + residual (h f32 in/out + bf16 copy) ----------------

__global__ __launch_bounds__(256, 2) void node_a_kernel(
    const float* __restrict__ h, const bf16* __restrict__ hbf_in,
    const float* __restrict__ accp, const float* __restrict__ accc,
    const float* __restrict__ invp, const float* __restrict__ invc,
    const float* __restrict__ pmask, const float* __restrict__ cmask,
    const float* __restrict__ stok, const float* __restrict__ etok,
    const bf16* __restrict__ W1t, const float* __restrict__ B1,
    const bf16* __restrict__ W2t, const float* __restrict__ B2,
    float* __restrict__ hout, bf16* __restrict__ hbf_out, int N) {
  __shared__ __attribute__((aligned(16))) bf16 x[EB * AS];  // [h | s_p | s_c]
  __shared__ __attribute__((aligned(16))) bf16 x2[EB * XS];
  const int t = threadIdx.x;
  const int r0 = blockIdx.x * EB;
  {
    const int r = t >> 3, c0 = (t & 7) * 16;
    int g = r0 + r; if (g >= N) g = N - 1;
    const bf16* src = hbf_in + (size_t)g * D_DIM + c0;
    *(bf16x8*)&x[r * AS + c0] = *(const bf16x8*)src;
    *(bf16x8*)&x[r * AS + c0 + 8] = *(const bf16x8*)(src + 8);
  }
  {
    const int j = t;  // cols 128..383
    for (int r = 0; r < EB; ++r) {
      int g = r0 + r; if (g >= N) g = N - 1;
      float v;
      if (j < 128)
        v = accp[(size_t)g * D_DIM + j] * invp[g] + pmask[g] * stok[j];
      else {
        int jj = j - 128;
        v = accc[(size_t)g * D_DIM + jj] * invc[g] + cmask[g] * etok[jj];
      }
      x[r * AS + 128 + j] = (bf16)v;
    }
  }
  __syncthreads();
  const int lane = t & 63, w = t >> 6, col = lane & 15, quad = lane >> 4;
  mlp_layer1<3>(x, x + 128, x + 256, AS, W1t, B1, x2, lane, w);
  __syncthreads();
  f32x4 acc2[2][2] = {};
  mlp_layer2(x2, W2t, lane, w, acc2);
#pragma unroll
  for (int nt = 0; nt < 2; ++nt) {
    const int n = w * 32 + nt * 16 + col;
    const float b2 = B2[n];
#pragma unroll
    for (int mt = 0; mt < 2; ++mt)
#pragma unroll
      for (int i = 0; i < 4; ++i) {
        int m = mt * 16 + quad * 4 + i;
        int g = r0 + m;
        if (g < N) {
          float mlpv = acc2[mt][nt][i] + b2;
          mlpv = mlpv > 0.f ? mlpv : 0.f;
          float v = h[(size_t)g * D_DIM + n] + mlpv;  // exact f32 residual
          v = v > 0.f ? v : 0.f;
          hout[(size_t)g * D_DIM + n] = v;
          hbf_out[(size_t)g * D_DIM + n] = (bf16)v;
        }
      }
  }
}

// ---------------- host launch ----------------

extern "C" void kernel_launch(void* const* d_in, const int* in_sizes, int n_in,
                              void* d_out, int out_size, void* d_ws, size_t ws_size,
                              hipStream_t stream) {
  const float* batch_token = (const float*)d_in[0];
  const int* epn = (const int*)d_in[1];
  const int* ecn = (const int*)d_in[2];
  const float* epi = (const float*)d_in[3];
  const float* eci = (const float*)d_in[4];
  const float* pmask = (const float*)d_in[5];
  const float* cmask = (const float*)d_in[6];
  const float* stok = (const float*)d_in[7];
  const float* etok = (const float*)d_in[8];
  const float *Vw1 = (const float*)d_in[9], *Vb1 = (const float*)d_in[10],
              *Vw2 = (const float*)d_in[11], *Vb2 = (const float*)d_in[12];
  const float *Ew1 = (const float*)d_in[13], *Eb1 = (const float*)d_in[14],
              *Ew2 = (const float*)d_in[15], *Eb2 = (const float*)d_in[16];
  const float *Pw1 = (const float*)d_in[17], *Pb1 = (const float*)d_in[18],
              *Pw2 = (const float*)d_in[19], *Pb2 = (const float*)d_in[20];
  const float *Cw1 = (const float*)d_in[21], *Cb1 = (const float*)d_in[22],
              *Cw2 = (const float*)d_in[23], *Cb2 = (const float*)d_in[24];
  const float *Aw1 = (const float*)d_in[25], *Ab1 = (const float*)d_in[26],
              *Aw2 = (const float*)d_in[27], *Ab2 = (const float*)d_in[28];
  const int N = in_sizes[5];  // p_mask length
  const int E = in_sizes[1];  // edge_p_node length

  char* ws = (char*)d_ws;
  size_t off = 0;
  auto alloc = [&](size_t bytes) {
    size_t o = off;
    off += (bytes + 511) & ~(size_t)511;
    return o;
  };
  float* accp = (float*)(ws + alloc((size_t)N * D_DIM * 4));
  float* accc = (float*)(ws + alloc((size_t)N * D_DIM * 4));
  bf16* hbf = (bf16*)(ws + alloc((size_t)N * D_DIM * 2));
  float* invp = (float*)(ws + alloc((size_t)N * 4));
  float* invc = (float*)(ws + alloc((size_t)N * 4));
  int* cntp = (int*)(ws + alloc((size_t)N * 4));
  int* cntc = (int*)(ws + alloc((size_t)N * 4));
  int* offp = (int*)(ws + alloc((size_t)N * 4));
  int* offc = (int*)(ws + alloc((size_t)N * 4));
  int* curp = (int*)(ws + alloc((size_t)N * 4));
  int* curc = (int*)(ws + alloc((size_t)N * 4));
  int* sortp = (int*)(ws + alloc((size_t)E * 4));
  int* sortc = (int*)(ws + alloc((size_t)E * 4));
  bf16* Vw1t = (bf16*)(ws + alloc(128 * 256 * 2));
  bf16* Pw1t = (bf16*)(ws + alloc(384 * 256 * 2));
  bf16* Cw1t = (bf16*)(ws + alloc(384 * 256 * 2));
  bf16* Aw1t = (bf16*)(ws + alloc(384 * 256 * 2));
  bf16* Vw2t = (bf16*)(ws + alloc(256 * 128 * 2));
  bf16* Ew2t = (bf16*)(ws + alloc(256 * 128 * 2));
  bf16* Pw2t = (bf16*)(ws + alloc(256 * 128 * 2));
  bf16* Cw2t = (bf16*)(ws + alloc(256 * 128 * 2));
  bf16* Aw2t = (bf16*)(ws + alloc(256 * 128 * 2));
  float* hbuf = (float*)d_out;  // h f32 lives in d_out across hops
  (void)ws_size; (void)n_in; (void)out_size;

  const dim3 blk(256);
  // weight transposes (f32 -> bf16): out[n*K+k] = in[k*N+n]
  transpose_kernel<<<dim3(1, 256), blk, 0, stream>>>(Vw1, Vw1t, 128, 256);
  transpose_kernel<<<dim3(2, 256), blk, 0, stream>>>(Pw1, Pw1t, 384, 256);
  transpose_kernel<<<dim3(2, 256), blk, 0, stream>>>(Cw1, Cw1t, 384, 256);
  transpose_kernel<<<dim3(2, 256), blk, 0, stream>>>(Aw1, Aw1t, 384, 256);
  transpose_kernel<<<dim3(1, 128), blk, 0, stream>>>(Vw2, Vw2t, 256, 128);
  transpose_kernel<<<dim3(1, 128), blk, 0, stream>>>(Ew2, Ew2t, 256, 128);
  transpose_kernel<<<dim3(1, 128), blk, 0, stream>>>(Pw2, Pw2t, 256, 128);
  transpose_kernel<<<dim3(1, 128), blk, 0, stream>>>(Cw2, Cw2t, 256, 128);
  transpose_kernel<<<dim3(1, 128), blk, 0, stream>>>(Aw2, Aw2t, 256, 128);

  // degree counts -> reciprocals; counting sort (hop-invariant)
  const size_t cntbytes = (size_t)((char*)(cntc + N) - (char*)cntp);
  hipMemsetAsync(cntp, 0, cntbytes, stream);
  count_kernel<<<dim3((E + 255) / 256), blk, 0, stream>>>(epn, ecn, cntp, cntc, E, N);
  inv_kernel<<<dim3((N + 255) / 256), blk, 0, stream>>>(cntp, cntc, invp, invc, N);
  scan_kernel<<<dim3(1), dim3(1024), 0, stream>>>(cntp, offp, N);
  scan_kernel<<<dim3(1), dim3(1024), 0, stream>>>(cntc, offc, N);
  const size_t curbytes = (size_t)((char*)(curc + N) - (char*)curp);
  hipMemsetAsync(curp, 0, curbytes, stream);
  scatter_kernel<<<dim3((E + 255) / 256), blk, 0, stream>>>(epn, ecn, offp, offc,
                                                            curp, curc, sortp, sortc, E, N);

  const int nblocks = (N + EB - 1) / EB;
  const int etiles = (E + EB - 1) / EB;
  const int egrid = (etiles + T_TILES - 1) / T_TILES;

  // h = MLP_V(batch_token)  (f32 into d_out + bf16 copy)
  node_v_kernel<<<dim3(nblocks), blk, 0, stream>>>(batch_token, Vw1t, Vb1, Vw2t, Vb2,
                                                   hbuf, hbf, N);

  const size_t accbytes = (size_t)((char*)(accc + (size_t)N * D_DIM) - (char*)accp);
  for (int hop = 0; hop < 3; ++hop) {
    hipMemsetAsync(accp, 0, accbytes, stream);
    edge_side_kernel<<<dim3(egrid, 2), blk, 0, stream>>>(
        hbf, epi, eci, epn, ecn, sortp, sortc, Ew1, Eb1, Ew2t, Eb2,
        Pw1t, Pb1, Pw2t, Pb2, Cw1t, Cb1, Cw2t, Cb2, accp, accc, E, N);
    node_a_kernel<<<dim3(nblocks), blk, 0, stream>>>(
        hbuf, hbf, accp, accc, invp, invc, pmask, cmask, stok, etok,
        Aw1t, Ab1, Aw2t, Ab2, hbuf, hbf, N);
  }
}

// Round 9
// 4857.739 us; speedup vs baseline: 1.0503x; 1.0503x over previous
//
#include <hip/hip_runtime.h>
#include <hip/hip_bf16.h>
#include <cstdint>
#include <cstddef>

typedef __bf16 bf16;
typedef bf16 bf16x8 __attribute__((ext_vector_type(8)));
typedef float f32x4 __attribute__((ext_vector_type(4)));

#define D_DIM 128
#define EB 32      // edges (or nodes) per tile
#define TS 136     // LDS stride for 128-wide bf16 tiles (+8 pad)
#define XS 264     // LDS stride for 256-wide x2 bf16 tile
#define SRS 132    // LDS stride for 128-wide f32 sred tile (aliased over x2)
#define AS 392     // LDS stride for 384-wide node-A input tile

__device__ __forceinline__ f32x4 mfma16(bf16x8 a, bf16x8 b, f32x4 c) {
  return __builtin_amdgcn_mfma_f32_16x16x32_bf16(a, b, c, 0, 0, 0);
}

__device__ __forceinline__ int clampi(int v, int hi) {
  return v < 0 ? 0 : (v > hi ? hi : v);
}

// stage 16 consecutive f32 (64B, aligned) -> 16 bf16 in LDS
__device__ __forceinline__ void stage16(const float* __restrict__ src, bf16* dst) {
  bf16 tmp[16];
#pragma unroll
  for (int q = 0; q < 4; ++q) {
    f32x4 f = ((const f32x4*)src)[q];
#pragma unroll
    for (int j = 0; j < 4; ++j) tmp[q * 4 + j] = (bf16)f[j];
  }
  *(bf16x8*)dst = *(bf16x8*)tmp;
  *(bf16x8*)(dst + 8) = *(bf16x8*)(tmp + 8);
}

// ---- layer1 (node kernels): A[32 x K] from LDS segments @ W1t[256 x K]^T -> x2
template <int NSEG>
__device__ __forceinline__ void mlp_layer1(const bf16* s0, const bf16* s1, const bf16* s2,
                                           const int S,
                                           const bf16* __restrict__ W1t,
                                           const float* __restrict__ B1,
                                           bf16* x2, const int lane, const int w) {
  const int col = lane & 15, quad = lane >> 4;
  const int K = NSEG * 128;
  f32x4 acc[2][4] = {};
  const bf16* segs[3] = {s0, s1, s2};
#pragma unroll
  for (int sg = 0; sg < NSEG; ++sg) {
    const bf16* xl = segs[sg];
#pragma unroll
    for (int kk = 0; kk < 128; kk += 32) {
      const int k0 = sg * 128 + kk;
      bf16x8 a0 = *(const bf16x8*)&xl[col * S + kk + quad * 8];
      bf16x8 a1 = *(const bf16x8*)&xl[(col + 16) * S + kk + quad * 8];
#pragma unroll
      for (int nt = 0; nt < 4; ++nt) {
        bf16x8 b = *(const bf16x8*)(W1t + (size_t)(w * 64 + nt * 16 + col) * K + k0 + quad * 8);
        acc[0][nt] = mfma16(a0, b, acc[0][nt]);
        acc[1][nt] = mfma16(a1, b, acc[1][nt]);
      }
    }
  }
#pragma unroll
  for (int nt = 0; nt < 4; ++nt) {
    const int n = w * 64 + nt * 16 + col;
    const float b1 = B1[n];
#pragma unroll
    for (int mt = 0; mt < 2; ++mt)
#pragma unroll
      for (int i = 0; i < 4; ++i) {
        float v = acc[mt][nt][i] + b1;
        x2[(mt * 16 + quad * 4 + i) * XS + n] = (bf16)(v > 0.f ? v : 0.f);
      }
  }
}

// ---- layer2: x2[32 x 256] @ W2t[128 x 256]^T -> acc2
__device__ __forceinline__ void mlp_layer2(const bf16* x2, const bf16* __restrict__ W2t,
                                           const int lane, const int w, f32x4 acc2[2][2]) {
  const int col = lane & 15, quad = lane >> 4;
#pragma unroll
  for (int k0 = 0; k0 < 256; k0 += 32) {
    bf16x8 a0 = *(const bf16x8*)&x2[col * XS + k0 + quad * 8];
    bf16x8 a1 = *(const bf16x8*)&x2[(col + 16) * XS + k0 + quad * 8];
#pragma unroll
    for (int nt = 0; nt < 2; ++nt) {
      bf16x8 b = *(const bf16x8*)(W2t + (size_t)(w * 32 + nt * 16 + col) * 256 + k0 + quad * 8);
      acc2[0][nt] = mfma16(a0, b, acc2[0][nt]);
      acc2[1][nt] = mfma16(a1, b, acc2[1][nt]);
    }
  }
}

// ---------------- small utility kernels ----------------

// f32 [K,N] -> bf16 [N,K]
__global__ void transpose_kernel(const float* __restrict__ in, bf16* __restrict__ out,
                                 int K, int N) {
  int k = blockIdx.x * blockDim.x + threadIdx.x;
  int n = blockIdx.y;
  if (k < K) out[(size_t)n * K + k] = (bf16)in[(size_t)k * N + n];
}

__global__ void count_kernel(const int* __restrict__ epn, const int* __restrict__ ecn,
                             int* cntp, int* cntc, int E, int N) {
  int i = blockIdx.x * blockDim.x + threadIdx.x;
  if (i < E) {
    atomicAdd(&cntp[clampi(epn[i], N - 1)], 1);
    atomicAdd(&cntc[clampi(ecn[i], N - 1)], 1);
  }
}

__global__ void inv_kernel(const int* __restrict__ cntp, const int* __restrict__ cntc,
                           float* invp, float* invc, int N) {
  int i = blockIdx.x * blockDim.x + threadIdx.x;
  if (i < N) {
    invp[i] = 1.f / fmaxf((float)cntp[i], 1.f);
    invc[i] = 1.f / fmaxf((float)cntc[i], 1.f);
  }
}

// single-block exclusive scan of cnt[n] -> offs[n]
__global__ void scan_kernel(const int* __restrict__ cnt, int* __restrict__ offs, int n) {
  __shared__ int buf[1024];
  __shared__ int carry;
  const int t = threadIdx.x;
  if (t == 0) carry = 0;
  __syncthreads();
  for (int base = 0; base < n; base += 1024) {
    int v = (base + t < n) ? cnt[base + t] : 0;
    buf[t] = v;
    __syncthreads();
    for (int d = 1; d < 1024; d <<= 1) {
      int add = (t >= d) ? buf[t - d] : 0;
      __syncthreads();
      buf[t] += add;
      __syncthreads();
    }
    if (base + t < n) offs[base + t] = carry + buf[t] - v;  // exclusive
    __syncthreads();
    if (t == 1023) carry += buf[1023];
    __syncthreads();
  }
}

// counting-sort scatter: edge ids grouped by destination node
__global__ void scatter_kernel(const int* __restrict__ epn, const int* __restrict__ ecn,
                               const int* __restrict__ offp, const int* __restrict__ offc,
                               int* curp, int* curc, int* sortp, int* sortc, int E, int N) {
  int i = blockIdx.x * blockDim.x + threadIdx.x;
  if (i < E) {
    int p = clampi(epn[i], N - 1);
    sortp[offp[p] + atomicAdd(&curp[p], 1)] = i;
    int c = clampi(ecn[i], N - 1);
    sortc[offc[c] + atomicAdd(&curc[c], 1)] = i;
  }
}

// ---------------- MLP_V: h = mlp(batch_token), h stored f32 + bf16 copy ----------------

__global__ __launch_bounds__(256, 2) void node_v_kernel(
    const float* __restrict__ bt, const bf16* __restrict__ W1t, const float* __restrict__ B1,
    const bf16* __restrict__ W2t, const float* __restrict__ B2,
    float* __restrict__ hout, bf16* __restrict__ hbf, int N) {
  __shared__ __attribute__((aligned(16))) bf16 x[EB * TS];
  __shared__ __attribute__((aligned(16))) bf16 x2[EB * XS];
  const int t = threadIdx.x;
  const int r0 = blockIdx.x * EB;
  {
    const int r = t >> 3, c0 = (t & 7) * 16;
    int g = r0 + r; if (g >= N) g = N - 1;
    stage16(bt + (size_t)g * D_DIM + c0, &x[r * TS + c0]);
  }
  __syncthreads();
  const int lane = t & 63, w = t >> 6, col = lane & 15, quad = lane >> 4;
  mlp_layer1<1>(x, x, x, TS, W1t, B1, x2, lane, w);
  __syncthreads();
  f32x4 acc2[2][2] = {};
  mlp_layer2(x2, W2t, lane, w, acc2);
#pragma unroll
  for (int nt = 0; nt < 2; ++nt) {
    const int n = w * 32 + nt * 16 + col;
    const float b2 = B2[n];
#pragma unroll
    for (int mt = 0; mt < 2; ++mt)
#pragma unroll
      for (int i = 0; i < 4; ++i) {
        int m = mt * 16 + quad * 4 + i;
        int g = r0 + m;
        if (g < N) {
          float v = acc2[mt][nt][i] + b2;
          v = v > 0.f ? v : 0.f;
          hout[(size_t)g * D_DIM + n] = v;
          hbf[(size_t)g * D_DIM + n] = (bf16)v;
        }
      }
  }
}

// ---------------- per-hop edge kernel: reg-gather A-operands, low LDS ----------------
// side 0 (P): s_p = MLP_P([hc, hp, ep]) summed by epn -> accp
// side 1 (C): s_c = MLP_C([hp, hc, ec]) summed by ecn -> accc

__global__ __launch_bounds__(256, 5) void edge_side_kernel(
    const bf16* __restrict__ hbf,
    const float* __restrict__ epi, const float* __restrict__ eci,
    const int* __restrict__ epn, const int* __restrict__ ecn,
    const int* __restrict__ sortp, const int* __restrict__ sortc,
    const float* __restrict__ Ew1, const float* __restrict__ Eb1,
    const bf16* __restrict__ Ew2t, const float* __restrict__ Eb2,
    const bf16* __restrict__ Pw1t, const float* __restrict__ Pb1,
    const bf16* __restrict__ Pw2t, const float* __restrict__ Pb2,
    const bf16* __restrict__ Cw1t, const float* __restrict__ Cb1,
    const bf16* __restrict__ Cw2t, const float* __restrict__ Cb2,
    float* __restrict__ accp, float* __restrict__ accc, int E, int N) {
  const int side = blockIdx.y;  // wave-uniform
  const float* ei    = side ? eci : epi;
  const int* own_n   = side ? ecn : epn;
  const int* oth_n   = side ? epn : ecn;
  const int* sorted  = side ? sortc : sortp;
  const bf16* W1t    = side ? Cw1t : Pw1t;
  const float* B1    = side ? Cb1 : Pb1;
  const bf16* W2t    = side ? Cw2t : Pw2t;
  const float* B2    = side ? Cb2 : Pb2;
  float* acc         = side ? accc : accp;

  __shared__ int s_own[EB], s_oth[EB];  // s_own doubles as segment key; -1 = pad
  __shared__ float s_x[EB];
  __shared__ float s_ew1[256], s_eb1[256];
  __shared__ __attribute__((aligned(16))) bf16 feat[EB * TS];      // 8704 B
  __shared__ __attribute__((aligned(16))) char xbuf[EB * XS * 2];  // 16896 B: x2 / sred
  bf16* x2 = (bf16*)xbuf;
  float* sred = (float*)xbuf;

  const int t = threadIdx.x;
  const int e0 = blockIdx.x * EB;
  if (t < EB) {
    int e = e0 + t;
    if (e < E) {
      int id = clampi(sorted[e], E - 1);
      s_own[t] = clampi(own_n[id], N - 1);
      s_oth[t] = clampi(oth_n[id], N - 1);
      s_x[t] = ei[id];
    } else {
      s_own[t] = -1; s_oth[t] = 0; s_x[t] = 0.f;
    }
  }
  s_ew1[t] = Ew1[t];
  s_eb1[t] = Eb1[t];
  __syncthreads();  // indices + E-layer1 weights ready

  const int lane = t & 63, w = t >> 6, col = lane & 15, quad = lane >> 4;

  // ---- issue h gathers straight into MFMA A-fragment registers (no LDS)
  // rows m0=col, m1=col+16 ; element k = kk*32 + quad*8
  bf16x8 a_ot[2][4], a_ow[2][4];
  {
    int no0 = s_oth[col], no1 = s_oth[col + 16];
    int nw0 = s_own[col], nw1 = s_own[col + 16];
    if (nw0 < 0) nw0 = 0;
    if (nw1 < 0) nw1 = 0;
    const bf16* p_ot0 = hbf + (size_t)no0 * D_DIM + quad * 8;
    const bf16* p_ot1 = hbf + (size_t)no1 * D_DIM + quad * 8;
    const bf16* p_ow0 = hbf + (size_t)nw0 * D_DIM + quad * 8;
    const bf16* p_ow1 = hbf + (size_t)nw1 * D_DIM + quad * 8;
#pragma unroll
    for (int kk = 0; kk < 4; ++kk) {
      a_ot[0][kk] = *(const bf16x8*)(p_ot0 + kk * 32);
      a_ot[1][kk] = *(const bf16x8*)(p_ot1 + kk * 32);
      a_ow[0][kk] = *(const bf16x8*)(p_ow0 + kk * 32);
      a_ow[1][kk] = *(const bf16x8*)(p_ow1 + kk * 32);
    }
  }

  // ---- edge-feature MLP (covers gather latency): feat tile [32 x 128]
  {
    const float xv0 = s_x[col];
    const float xv1 = s_x[col + 16];
    f32x4 fa[2][2] = {};
#pragma unroll
    for (int k0 = 0; k0 < 256; k0 += 32) {
      const int kb = k0 + quad * 8;
      f32x4 e0 = *(const f32x4*)&s_ew1[kb];
      f32x4 e1 = *(const f32x4*)&s_ew1[kb + 4];
      f32x4 b0 = *(const f32x4*)&s_eb1[kb];
      f32x4 b1 = *(const f32x4*)&s_eb1[kb + 4];
      bf16 a0v[8], a1v[8];
#pragma unroll
      for (int j = 0; j < 4; ++j) {
        float v;
        v = xv0 * e0[j] + b0[j]; a0v[j]     = (bf16)(v > 0.f ? v : 0.f);
        v = xv0 * e1[j] + b1[j]; a0v[4 + j] = (bf16)(v > 0.f ? v : 0.f);
        v = xv1 * e0[j] + b0[j]; a1v[j]     = (bf16)(v > 0.f ? v : 0.f);
        v = xv1 * e1[j] + b1[j]; a1v[4 + j] = (bf16)(v > 0.f ? v : 0.f);
      }
      bf16x8 a0 = *(bf16x8*)a0v, a1 = *(bf16x8*)a1v;
#pragma unroll
      for (int nt = 0; nt < 2; ++nt) {
        bf16x8 b = *(const bf16x8*)(Ew2t + (size_t)(w * 32 + nt * 16 + col) * 256 + k0 + quad * 8);
        fa[0][nt] = mfma16(a0, b, fa[0][nt]);
        fa[1][nt] = mfma16(a1, b, fa[1][nt]);
      }
    }
#pragma unroll
    for (int nt = 0; nt < 2; ++nt) {
      const int n = w * 32 + nt * 16 + col;
      const float b2 = Eb2[n];
#pragma unroll
      for (int mt = 0; mt < 2; ++mt)
#pragma unroll
        for (int i = 0; i < 4; ++i) {
          float v = fa[mt][nt][i] + b2;
          feat[(mt * 16 + quad * 4 + i) * TS + n] = (bf16)(v > 0.f ? v : 0.f);
        }
    }
  }
  __syncthreads();  // feat visible

  // ---- layer1: segs {oth(regs), own(regs), feat(LDS)} @ W1t[256 x 384]
  {
    f32x4 acc1[2][4] = {};
#pragma unroll
    for (int kk = 0; kk < 4; ++kk) {
#pragma unroll
      for (int nt = 0; nt < 4; ++nt) {
        bf16x8 b = *(const bf16x8*)(W1t + (size_t)(w * 64 + nt * 16 + col) * 384 + kk * 32 + quad * 8);
        acc1[0][nt] = mfma16(a_ot[0][kk], b, acc1[0][nt]);
        acc1[1][nt] = mfma16(a_ot[1][kk], b, acc1[1][nt]);
      }
    }
#pragma unroll
    for (int kk = 0; kk < 4; ++kk) {
#pragma unroll
      for (int nt = 0; nt < 4; ++nt) {
        bf16x8 b = *(const bf16x8*)(W1t + (size_t)(w * 64 + nt * 16 + col) * 384 + 128 + kk * 32 + quad * 8);
        acc1[0][nt] = mfma16(a_ow[0][kk], b, acc1[0][nt]);
        acc1[1][nt] = mfma16(a_ow[1][kk], b, acc1[1][nt]);
      }
    }
#pragma unroll
    for (int kk = 0; kk < 4; ++kk) {
      bf16x8 a0 = *(const bf16x8*)&feat[col * TS + kk * 32 + quad * 8];
      bf16x8 a1 = *(const bf16x8*)&feat[(col + 16) * TS + kk * 32 + quad * 8];
#pragma unroll
      for (int nt = 0; nt < 4; ++nt) {
        bf16x8 b = *(const bf16x8*)(W1t + (size_t)(w * 64 + nt * 16 + col) * 384 + 256 + kk * 32 + quad * 8);
        acc1[0][nt] = mfma16(a0, b, acc1[0][nt]);
        acc1[1][nt] = mfma16(a1, b, acc1[1][nt]);
      }
    }
#pragma unroll
    for (int nt = 0; nt < 4; ++nt) {
      const int n = w * 64 + nt * 16 + col;
      const float b1 = B1[n];
#pragma unroll
      for (int mt = 0; mt < 2; ++mt)
#pragma unroll
        for (int i = 0; i < 4; ++i) {
          float v = acc1[mt][nt][i] + b1;
          x2[(mt * 16 + quad * 4 + i) * XS + n] = (bf16)(v > 0.f ? v : 0.f);
        }
    }
  }
  __syncthreads();  // x2 visible

  f32x4 acc2[2][2] = {};
  mlp_layer2(x2, W2t, lane, w, acc2);
  __syncthreads();  // all x2 reads done before sred aliases it

  // ---- sred write + wave-private segmented reduce (wave w owns cols w*32..+31)
#pragma unroll
  for (int nt = 0; nt < 2; ++nt) {
    const int n = w * 32 + nt * 16 + col;
    const float b2 = B2[n];
#pragma unroll
    for (int mt = 0; mt < 2; ++mt)
#pragma unroll
      for (int i = 0; i < 4; ++i) {
        float v = acc2[mt][nt][i] + b2;
        sred[(mt * 16 + quad * 4 + i) * SRS + n] = v > 0.f ? v : 0.f;
      }
  }
  {
    const int c = w * 32 + (lane >> 1);
    const int rlo = (lane & 1) * 16;
    float run = 0.f;
    int cur = s_own[rlo];
    for (int r = rlo; r < rlo + 16; ++r) {
      int k = s_own[r];
      if (k != cur) {
        if (cur >= 0)
          __hip_atomic_fetch_add(&acc[(size_t)cur * D_DIM + c], run,
                                 __ATOMIC_RELAXED, __HIP_MEMORY_SCOPE_AGENT);
        run = 0.f;
        cur = k;
      }
      run += sred[r * SRS + c];
    }
    if (cur >= 0)
      __hip_atomic_fetch_add(&acc[(size_t)cur * D_DIM + c], run,
                             __ATOMIC_RELAXED, __HIP_MEMORY_SCOPE_AGENT);
  }
}

// ---------------- per-hop node kernel: MLP_A + residual (h f32 in/out + bf16 copy) ----------------

__global__ __launch_bounds__(256, 2) void node_a_kernel(
    const float* __restrict__ h, const bf16* __restrict__ hbf_in,
    const float* __restrict__ accp, const float* __restrict__ accc,
    const float* __restrict__ invp, const float* __restrict__ invc,
    const float* __restrict__ pmask, const float* __restrict__ cmask,
    const float* __restrict__ stok, const float* __restrict__ etok,
    const bf16* __restrict__ W1t, const float* __restrict__ B1,
    const bf16* __restrict__ W2t, const float* __restrict__ B2,
    float* __restrict__ hout, bf16* __restrict__ hbf_out, int N) {
  __shared__ __attribute__((aligned(16))) bf16 x[EB * AS];  // [h | s_p | s_c]
  __shared__ __attribute__((aligned(16))) bf16 x2[EB * XS];
  const int t = threadIdx.x;
  const int r0 = blockIdx.x * EB;
  {
    const int r = t >> 3, c0 = (t & 7) * 16;
    int g = r0 + r; if (g >= N) g = N - 1;
    const bf16* src = hbf_in + (size_t)g * D_DIM + c0;
    *(bf16x8*)&x[r * AS + c0] = *(const bf16x8*)src;
    *(bf16x8*)&x[r * AS + c0 + 8] = *(const bf16x8*)(src + 8);
  }
  {
    const int j = t;  // cols 128..383
    for (int r = 0; r < EB; ++r) {
      int g = r0 + r; if (g >= N) g = N - 1;
      float v;
      if (j < 128)
        v = accp[(size_t)g * D_DIM + j] * invp[g] + pmask[g] * stok[j];
      else {
        int jj = j - 128;
        v = accc[(size_t)g * D_DIM + jj] * invc[g] + cmask[g] * etok[jj];
      }
      x[r * AS + 128 + j] = (bf16)v;
    }
  }
  __syncthreads();
  const int lane = t & 63, w = t >> 6, col = lane & 15, quad = lane >> 4;
  mlp_layer1<3>(x, x + 128, x + 256, AS, W1t, B1, x2, lane, w);
  __syncthreads();
  f32x4 acc2[2][2] = {};
  mlp_layer2(x2, W2t, lane, w, acc2);
#pragma unroll
  for (int nt = 0; nt < 2; ++nt) {
    const int n = w * 32 + nt * 16 + col;
    const float b2 = B2[n];
#pragma unroll
    for (int mt = 0; mt < 2; ++mt)
#pragma unroll
      for (int i = 0; i < 4; ++i) {
        int m = mt * 16 + quad * 4 + i;
        int g = r0 + m;
        if (g < N) {
          float mlpv = acc2[mt][nt][i] + b2;
          mlpv = mlpv > 0.f ? mlpv : 0.f;
          float v = h[(size_t)g * D_DIM + n] + mlpv;  // exact f32 residual
          v = v > 0.f ? v : 0.f;
          hout[(size_t)g * D_DIM + n] = v;
          hbf_out[(size_t)g * D_DIM + n] = (bf16)v;
        }
      }
  }
}

// ---------------- host launch ----------------

extern "C" void kernel_launch(void* const* d_in, const int* in_sizes, int n_in,
                              void* d_out, int out_size, void* d_ws, size_t ws_size,
                              hipStream_t stream) {
  const float* batch_token = (const float*)d_in[0];
  const int* epn = (const int*)d_in[1];
  const int* ecn = (const int*)d_in[2];
  const float* epi = (const float*)d_in[3];
  const float* eci = (const float*)d_in[4];
  const float* pmask = (const float*)d_in[5];
  const float* cmask = (const float*)d_in[6];
  const float* stok = (const float*)d_in[7];
  const float* etok = (const float*)d_in[8];
  const float *Vw1 = (const float*)d_in[9], *Vb1 = (const float*)d_in[10],
              *Vw2 = (const float*)d_in[11], *Vb2 = (const float*)d_in[12];
  const float *Ew1 = (const float*)d_in[13], *Eb1 = (const float*)d_in[14],
              *Ew2 = (const float*)d_in[15], *Eb2 = (const float*)d_in[16];
  const float *Pw1 = (const float*)d_in[17], *Pb1 = (const float*)d_in[18],
              *Pw2 = (const float*)d_in[19], *Pb2 = (const float*)d_in[20];
  const float *Cw1 = (const float*)d_in[21], *Cb1 = (const float*)d_in[22],
              *Cw2 = (const float*)d_in[23], *Cb2 = (const float*)d_in[24];
  const float *Aw1 = (const float*)d_in[25], *Ab1 = (const float*)d_in[26],
              *Aw2 = (const float*)d_in[27], *Ab2 = (const float*)d_in[28];
  const int N = in_sizes[5];  // p_mask length
  const int E = in_sizes[1];  // edge_p_node length

  char* ws = (char*)d_ws;
  size_t off = 0;
  auto alloc = [&](size_t bytes) {
    size_t o = off;
    off += (bytes + 511) & ~(size_t)511;
    return o;
  };
  float* accp = (float*)(ws + alloc((size_t)N * D_DIM * 4));
  float* accc = (float*)(ws + alloc((size_t)N * D_DIM * 4));
  bf16* hbf = (bf16*)(ws + alloc((size_t)N * D_DIM * 2));
  float* invp = (float*)(ws + alloc((size_t)N * 4));
  float* invc = (float*)(ws + alloc((size_t)N * 4));
  int* cntp = (int*)(ws + alloc((size_t)N * 4));
  int* cntc = (int*)(ws + alloc((size_t)N * 4));
  int* offp = (int*)(ws + alloc((size_t)N * 4));
  int* offc = (int*)(ws + alloc((size_t)N * 4));
  int* curp = (int*)(ws + alloc((size_t)N * 4));
  int* curc = (int*)(ws + alloc((size_t)N * 4));
  int* sortp = (int*)(ws + alloc((size_t)E * 4));
  int* sortc = (int*)(ws + alloc((size_t)E * 4));
  bf16* Vw1t = (bf16*)(ws + alloc(128 * 256 * 2));
  bf16* Pw1t = (bf16*)(ws + alloc(384 * 256 * 2));
  bf16* Cw1t = (bf16*)(ws + alloc(384 * 256 * 2));
  bf16* Aw1t = (bf16*)(ws + alloc(384 * 256 * 2));
  bf16* Vw2t = (bf16*)(ws + alloc(256 * 128 * 2));
  bf16* Ew2t = (bf16*)(ws + alloc(256 * 128 * 2));
  bf16* Pw2t = (bf16*)(ws + alloc(256 * 128 * 2));
  bf16* Cw2t = (bf16*)(ws + alloc(256 * 128 * 2));
  bf16* Aw2t = (bf16*)(ws + alloc(256 * 128 * 2));
  float* hbuf = (float*)d_out;  // h f32 lives in d_out across hops
  (void)ws_size; (void)n_in; (void)out_size;

  const dim3 blk(256);
  // weight transposes (f32 -> bf16): out[n*K+k] = in[k*N+n]
  transpose_kernel<<<dim3(1, 256), blk, 0, stream>>>(Vw1, Vw1t, 128, 256);
  transpose_kernel<<<dim3(2, 256), blk, 0, stream>>>(Pw1, Pw1t, 384, 256);
  transpose_kernel<<<dim3(2, 256), blk, 0, stream>>>(Cw1, Cw1t, 384, 256);
  transpose_kernel<<<dim3(2, 256), blk, 0, stream>>>(Aw1, Aw1t, 384, 256);
  transpose_kernel<<<dim3(1, 128), blk, 0, stream>>>(Vw2, Vw2t, 256, 128);
  transpose_kernel<<<dim3(1, 128), blk, 0, stream>>>(Ew2, Ew2t, 256, 128);
  transpose_kernel<<<dim3(1, 128), blk, 0, stream>>>(Pw2, Pw2t, 256, 128);
  transpose_kernel<<<dim3(1, 128), blk, 0, stream>>>(Cw2, Cw2t, 256, 128);
  transpose_kernel<<<dim3(1, 128), blk, 0, stream>>>(Aw2, Aw2t, 256, 128);

  // degree counts -> reciprocals; counting sort (hop-invariant)
  const size_t cntbytes = (size_t)((char*)(cntc + N) - (char*)cntp);
  hipMemsetAsync(cntp, 0, cntbytes, stream);
  count_kernel<<<dim3((E + 255) / 256), blk, 0, stream>>>(epn, ecn, cntp, cntc, E, N);
  inv_kernel<<<dim3((N + 255) / 256), blk, 0, stream>>>(cntp, cntc, invp, invc, N);
  scan_kernel<<<dim3(1), dim3(1024), 0, stream>>>(cntp, offp, N);
  scan_kernel<<<dim3(1), dim3(1024), 0, stream>>>(cntc, offc, N);
  const size_t curbytes = (size_t)((char*)(curc + N) - (char*)curp);
  hipMemsetAsync(curp, 0, curbytes, stream);
  scatter_kernel<<<dim3((E + 255) / 256), blk, 0, stream>>>(epn, ecn, offp, offc,
                                                            curp, curc, sortp, sortc, E, N);

  const int nblocks = (N + EB - 1) / EB;
  const int eblocks = (E + EB - 1) / EB;

  // h = MLP_V(batch_token)  (f32 into d_out + bf16 copy)
  node_v_kernel<<<dim3(nblocks), blk, 0, stream>>>(batch_token, Vw1t, Vb1, Vw2t, Vb2,
                                                   hbuf, hbf, N);

  const size_t accbytes = (size_t)((char*)(accc + (size_t)N * D_DIM) - (char*)accp);
  for (int hop = 0; hop < 3; ++hop) {
    hipMemsetAsync(accp, 0, accbytes, stream);
    edge_side_kernel<<<dim3(eblocks, 2), blk, 0, stream>>>(
        hbf, epi, eci, epn, ecn, sortp, sortc, Ew1, Eb1, Ew2t, Eb2,
        Pw1t, Pb1, Pw2t, Pb2, Cw1t, Cb1, Cw2t, Cb2, accp, accc, E, N);
    node_a_kernel<<<dim3(nblocks), blk, 0, stream>>>(
        hbuf, hbf, accp, accc, invp, invc, pmask, cmask, stok, etok,
        Aw1t, Ab1, Aw2t, Ab2, hbuf, hbf, N);
  }
}

// Round 10
// 2601.354 us; speedup vs baseline: 1.9614x; 1.8674x over previous
//
#include <hip/hip_runtime.h>
#include <hip/hip_bf16.h>
#include <cstdint>
#include <cstddef>

typedef __bf16 bf16;
typedef bf16 bf16x8 __attribute__((ext_vector_type(8)));
typedef float f32x4 __attribute__((ext_vector_type(4)));

#define D_DIM 128
#define NB 32      // nodes per tile (node kernels)
#define EB 64      // edges per tile (edge kernel)
#define TS 136     // LDS stride for 128-wide bf16 tiles (+8 pad)
#define XS 264     // LDS stride for 256-wide bf16 tile (+8 pad)
#define SRS 132    // LDS stride for 128-wide f32 sred tile (aliases xz)
#define AS 392     // LDS stride for 384-wide node-A input tile

__device__ __forceinline__ f32x4 mfma16(bf16x8 a, bf16x8 b, f32x4 c) {
  return __builtin_amdgcn_mfma_f32_16x16x32_bf16(a, b, c, 0, 0, 0);
}

__device__ __forceinline__ int clampi(int v, int hi) {
  return v < 0 ? 0 : (v > hi ? hi : v);
}

// stage 16 consecutive f32 (64B, aligned) -> 16 bf16 in LDS
__device__ __forceinline__ void stage16(const float* __restrict__ src, bf16* dst) {
  bf16 tmp[16];
#pragma unroll
  for (int q = 0; q < 4; ++q) {
    f32x4 f = ((const f32x4*)src)[q];
#pragma unroll
    for (int j = 0; j < 4; ++j) tmp[q * 4 + j] = (bf16)f[j];
  }
  *(bf16x8*)dst = *(bf16x8*)tmp;
  *(bf16x8*)(dst + 8) = *(bf16x8*)(tmp + 8);
}

// ---- layer1 (node kernels): A[32 x K] from LDS segments @ W1t[256 x K]^T -> x2
template <int NSEG>
__device__ __forceinline__ void mlp_layer1(const bf16* s0, const bf16* s1, const bf16* s2,
                                           const int S,
                                           const bf16* __restrict__ W1t,
                                           const float* __restrict__ B1,
                                           bf16* x2, const int lane, const int w) {
  const int col = lane & 15, quad = lane >> 4;
  const int K = NSEG * 128;
  f32x4 acc[2][4] = {};
  const bf16* segs[3] = {s0, s1, s2};
#pragma unroll
  for (int sg = 0; sg < NSEG; ++sg) {
    const bf16* xl = segs[sg];
#pragma unroll
    for (int kk = 0; kk < 128; kk += 32) {
      const int k0 = sg * 128 + kk;
      bf16x8 a0 = *(const bf16x8*)&xl[col * S + kk + quad * 8];
      bf16x8 a1 = *(const bf16x8*)&xl[(col + 16) * S + kk + quad * 8];
#pragma unroll
      for (int nt = 0; nt < 4; ++nt) {
        bf16x8 b = *(const bf16x8*)(W1t + (size_t)(w * 64 + nt * 16 + col) * K + k0 + quad * 8);
        acc[0][nt] = mfma16(a0, b, acc[0][nt]);
        acc[1][nt] = mfma16(a1, b, acc[1][nt]);
      }
    }
  }
#pragma unroll
  for (int nt = 0; nt < 4; ++nt) {
    const int n = w * 64 + nt * 16 + col;
    const float b1 = B1[n];
#pragma unroll
    for (int mt = 0; mt < 2; ++mt)
#pragma unroll
      for (int i = 0; i < 4; ++i) {
        float v = acc[mt][nt][i] + b1;
        x2[(mt * 16 + quad * 4 + i) * XS + n] = (bf16)(v > 0.f ? v : 0.f);
      }
  }
}

// ---- layer2: x2[32 x 256] @ W2t[128 x 256]^T -> acc2
__device__ __forceinline__ void mlp_layer2(const bf16* x2, const bf16* __restrict__ W2t,
                                           const int lane, const int w, f32x4 acc2[2][2]) {
  const int col = lane & 15, quad = lane >> 4;
#pragma unroll
  for (int k0 = 0; k0 < 256; k0 += 32) {
    bf16x8 a0 = *(const bf16x8*)&x2[col * XS + k0 + quad * 8];
    bf16x8 a1 = *(const bf16x8*)&x2[(col + 16) * XS + k0 + quad * 8];
#pragma unroll
    for (int nt = 0; nt < 2; ++nt) {
      bf16x8 b = *(const bf16x8*)(W2t + (size_t)(w * 32 + nt * 16 + col) * 256 + k0 + quad * 8);
      acc2[0][nt] = mfma16(a0, b, acc2[0][nt]);
      acc2[1][nt] = mfma16(a1, b, acc2[1][nt]);
    }
  }
}

// ---------------- small utility kernels ----------------

// f32 [K,N] -> bf16 [N,K]
__global__ void transpose_kernel(const float* __restrict__ in, bf16* __restrict__ out,
                                 int K, int N) {
  int k = blockIdx.x * blockDim.x + threadIdx.x;
  int n = blockIdx.y;
  if (k < K) out[(size_t)n * K + k] = (bf16)in[(size_t)k * N + n];
}

__global__ void count_kernel(const int* __restrict__ epn, const int* __restrict__ ecn,
                             int* cntp, int* cntc, int E, int N) {
  int i = blockIdx.x * blockDim.x + threadIdx.x;
  if (i < E) {
    atomicAdd(&cntp[clampi(epn[i], N - 1)], 1);
    atomicAdd(&cntc[clampi(ecn[i], N - 1)], 1);
  }
}

__global__ void inv_kernel(const int* __restrict__ cntp, const int* __restrict__ cntc,
                           float* invp, float* invc, int N) {
  int i = blockIdx.x * blockDim.x + threadIdx.x;
  if (i < N) {
    invp[i] = 1.f / fmaxf((float)cntp[i], 1.f);
    invc[i] = 1.f / fmaxf((float)cntc[i], 1.f);
  }
}

// single-block exclusive scan of cnt[n] -> offs[n]
__global__ void scan_kernel(const int* __restrict__ cnt, int* __restrict__ offs, int n) {
  __shared__ int buf[1024];
  __shared__ int carry;
  const int t = threadIdx.x;
  if (t == 0) carry = 0;
  __syncthreads();
  for (int base = 0; base < n; base += 1024) {
    int v = (base + t < n) ? cnt[base + t] : 0;
    buf[t] = v;
    __syncthreads();
    for (int d = 1; d < 1024; d <<= 1) {
      int add = (t >= d) ? buf[t - d] : 0;
      __syncthreads();
      buf[t] += add;
      __syncthreads();
    }
    if (base + t < n) offs[base + t] = carry + buf[t] - v;  // exclusive
    __syncthreads();
    if (t == 1023) carry += buf[1023];
    __syncthreads();
  }
}

// counting-sort scatter: edge ids grouped by destination node
__global__ void scatter_kernel(const int* __restrict__ epn, const int* __restrict__ ecn,
                               const int* __restrict__ offp, const int* __restrict__ offc,
                               int* curp, int* curc, int* sortp, int* sortc, int E, int N) {
  int i = blockIdx.x * blockDim.x + threadIdx.x;
  if (i < E) {
    int p = clampi(epn[i], N - 1);
    sortp[offp[p] + atomicAdd(&curp[p], 1)] = i;
    int c = clampi(ecn[i], N - 1);
    sortc[offc[c] + atomicAdd(&curc[c], 1)] = i;
  }
}

// ---------------- MLP_V: h = mlp(batch_token), h stored f32 ----------------

__global__ __launch_bounds__(256, 2) void node_v_kernel(
    const float* __restrict__ bt, const bf16* __restrict__ W1t, const float* __restrict__ B1,
    const bf16* __restrict__ W2t, const float* __restrict__ B2, float* __restrict__ hout, int N) {
  __shared__ __attribute__((aligned(16))) bf16 x[NB * TS];
  __shared__ __attribute__((aligned(16))) bf16 x2[NB * XS];
  const int t = threadIdx.x;
  const int r0 = blockIdx.x * NB;
  {
    const int r = t >> 3, c0 = (t & 7) * 16;
    int g = r0 + r; if (g >= N) g = N - 1;
    stage16(bt + (size_t)g * D_DIM + c0, &x[r * TS + c0]);
  }
  __syncthreads();
  const int lane = t & 63, w = t >> 6, col = lane & 15, quad = lane >> 4;
  mlp_layer1<1>(x, x, x, TS, W1t, B1, x2, lane, w);
  __syncthreads();
  f32x4 acc2[2][2] = {};
  mlp_layer2(x2, W2t, lane, w, acc2);
#pragma unroll
  for (int nt = 0; nt < 2; ++nt) {
    const int n = w * 32 + nt * 16 + col;
    const float b2 = B2[n];
#pragma unroll
    for (int mt = 0; mt < 2; ++mt)
#pragma unroll
      for (int i = 0; i < 4; ++i) {
        int m = mt * 16 + quad * 4 + i;
        int g = r0 + m;
        if (g < N) {
          float v = acc2[mt][nt][i] + b2;
          hout[(size_t)g * D_DIM + n] = v > 0.f ? v : 0.f;
        }
      }
  }
}

// ---------------- per-hop Z-GEMM: Z[w] = h @ W1-slice, w in {P-oth,P-own,C-oth,C-own} ----

__global__ __launch_bounds__(256, 3) void zgemm_kernel(
    const float* __restrict__ h,
    const bf16* __restrict__ Pw1t, const bf16* __restrict__ Cw1t,
    bf16* __restrict__ Zbuf, int N) {
  __shared__ __attribute__((aligned(16))) bf16 x[NB * TS];
  const int t = threadIdx.x;
  const int r0 = blockIdx.x * NB;
  {
    const int r = t >> 3, c0 = (t & 7) * 16;
    int g = r0 + r; if (g >= N) g = N - 1;
    stage16(h + (size_t)g * D_DIM + c0, &x[r * TS + c0]);
  }
  __syncthreads();
  const int lane = t & 63, w = t >> 6, col = lane & 15, quad = lane >> 4;
  const bf16* base = ((w & 2) ? Cw1t : Pw1t) + (w & 1) * 128;  // k-offset slice, row-stride 384
  bf16* out = Zbuf + (size_t)w * ((size_t)N * 256);
#pragma unroll
  for (int half = 0; half < 2; ++half) {
    f32x4 acc[2][8] = {};
#pragma unroll
    for (int kc = 0; kc < 4; ++kc) {
      bf16x8 a0 = *(const bf16x8*)&x[col * TS + kc * 32 + quad * 8];
      bf16x8 a1 = *(const bf16x8*)&x[(col + 16) * TS + kc * 32 + quad * 8];
#pragma unroll
      for (int nt = 0; nt < 8; ++nt) {
        const int n = half * 128 + nt * 16 + col;
        bf16x8 b = *(const bf16x8*)(base + (size_t)n * 384 + kc * 32 + quad * 8);
        acc[0][nt] = mfma16(a0, b, acc[0][nt]);
        acc[1][nt] = mfma16(a1, b, acc[1][nt]);
      }
    }
#pragma unroll
    for (int nt = 0; nt < 8; ++nt) {
      const int n = half * 128 + nt * 16 + col;
#pragma unroll
      for (int mt = 0; mt < 2; ++mt)
#pragma unroll
        for (int i = 0; i < 4; ++i) {
          int g = r0 + mt * 16 + quad * 4 + i;
          if (g < N) out[(size_t)g * 256 + n] = (bf16)acc[mt][nt][i];
        }
    }
  }
}

// ---------------- per-hop edge kernel (decomposed): EB=64, one side per blockIdx.y ----
// z(e) = ZO[oth(e)] + ZW[own(e)] + W1c*ep(e) + b1 ; out = relu(z) @ W2 ; segsum by own.

__global__ __launch_bounds__(256, 3) void edge_side_kernel(
    const bf16* __restrict__ Zbuf,
    const float* __restrict__ epi, const float* __restrict__ eci,
    const int* __restrict__ epn, const int* __restrict__ ecn,
    const int* __restrict__ sortp, const int* __restrict__ sortc,
    const float* __restrict__ Ew1, const float* __restrict__ Eb1,
    const bf16* __restrict__ Ew2t, const float* __restrict__ Eb2,
    const bf16* __restrict__ Pw1t, const float* __restrict__ Pb1,
    const bf16* __restrict__ Pw2t, const float* __restrict__ Pb2,
    const bf16* __restrict__ Cw1t, const float* __restrict__ Cb1,
    const bf16* __restrict__ Cw2t, const float* __restrict__ Cb2,
    float* __restrict__ accp, float* __restrict__ accc, int E, int N) {
  const int side = blockIdx.y;  // wave-uniform
  const size_t NZ = (size_t)N * 256;
  const bf16* ZO     = Zbuf + (size_t)(side * 2 + 0) * NZ;
  const bf16* ZW     = Zbuf + (size_t)(side * 2 + 1) * NZ;
  const float* ei    = side ? eci : epi;
  const int* own_n   = side ? ecn : epn;
  const int* oth_n   = side ? epn : ecn;
  const int* sorted  = side ? sortc : sortp;
  const bf16* W1c    = (side ? Cw1t : Pw1t) + 256;  // ep-slice, row-stride 384
  const float* B1    = side ? Cb1 : Pb1;
  const bf16* W2t    = side ? Cw2t : Pw2t;
  const float* B2    = side ? Cb2 : Pb2;
  float* acc         = side ? accc : accp;

  __shared__ int s_own[EB], s_oth[EB];  // s_own doubles as segment key; -1 = pad
  __shared__ float s_x[EB];
  __shared__ __attribute__((aligned(16))) bf16 feat[EB * TS];      // 17408 B
  __shared__ __attribute__((aligned(16))) char xbuf[EB * XS * 2];  // 33792 B: zsum/x2 bf16, sred f32
  bf16* xz = (bf16*)xbuf;
  float* sred = (float*)xbuf;

  const int t = threadIdx.x;
  const int e0 = blockIdx.x * EB;
  if (t < EB) {
    int e = e0 + t;
    if (e < E) {
      int id = clampi(sorted[e], E - 1);
      s_own[t] = clampi(own_n[id], N - 1);
      s_oth[t] = clampi(oth_n[id], N - 1);
      s_x[t] = ei[id];
    } else {
      s_own[t] = -1; s_oth[t] = 0; s_x[t] = 0.f;
    }
  }
  __syncthreads();  // barrier 0: indices ready

  const int lane = t & 63, w = t >> 6, col = lane & 15, quad = lane >> 4;

  // ---- zsum staging: xz[m][n] = bf16( ZO[oth] + ZW[own] )   (4 threads/row, 64 cols each)
  {
    const int zr = t >> 2, zc = (t & 3) * 64;
    int ro = s_oth[zr];
    int rw = s_own[zr]; if (rw < 0) rw = 0;
    const bf16* po = ZO + (size_t)ro * 256 + zc;
    const bf16* pw = ZW + (size_t)rw * 256 + zc;
#pragma unroll
    for (int cc = 0; cc < 64; cc += 8) {
      bf16x8 a = *(const bf16x8*)(po + cc);
      bf16x8 b = *(const bf16x8*)(pw + cc);
      bf16 o[8];
#pragma unroll
      for (int j = 0; j < 8; ++j) o[j] = (bf16)((float)a[j] + (float)b[j]);
      *(bf16x8*)&xz[zr * XS + zc + cc] = *(bf16x8*)o;
    }
  }

  // ---- E-MLP: feat[64 x 128] = relu(Ew2 @ relu(x*ew1+eb1) + eb2)  (wave w: cols w*32..+31)
  {
    float xv[4];
#pragma unroll
    for (int g = 0; g < 4; ++g) xv[g] = s_x[g * 16 + col];
    f32x4 fa[4][2] = {};
#pragma unroll
    for (int kc = 0; kc < 8; ++kc) {
      const int kb = kc * 32 + quad * 8;
      f32x4 e0 = *(const f32x4*)(Ew1 + kb);
      f32x4 e1 = *(const f32x4*)(Ew1 + kb + 4);
      f32x4 b0 = *(const f32x4*)(Eb1 + kb);
      f32x4 b1 = *(const f32x4*)(Eb1 + kb + 4);
      bf16x8 afr[4];
#pragma unroll
      for (int g = 0; g < 4; ++g) {
        bf16 av[8];
#pragma unroll
        for (int j = 0; j < 4; ++j) {
          float v0 = xv[g] * e0[j] + b0[j];
          float v1 = xv[g] * e1[j] + b1[j];
          av[j] = (bf16)(v0 > 0.f ? v0 : 0.f);
          av[4 + j] = (bf16)(v1 > 0.f ? v1 : 0.f);
        }
        afr[g] = *(bf16x8*)av;
      }
#pragma unroll
      for (int nt = 0; nt < 2; ++nt) {
        bf16x8 b = *(const bf16x8*)(Ew2t + (size_t)(w * 32 + nt * 16 + col) * 256 + kb);
#pragma unroll
        for (int g = 0; g < 4; ++g) fa[g][nt] = mfma16(afr[g], b, fa[g][nt]);
      }
    }
#pragma unroll
    for (int nt = 0; nt < 2; ++nt) {
      const int n = w * 32 + nt * 16 + col;
      const float b2 = Eb2[n];
#pragma unroll
      for (int g = 0; g < 4; ++g)
#pragma unroll
        for (int i = 0; i < 4; ++i) {
          float v = fa[g][nt][i] + b2;
          feat[(g * 16 + quad * 4 + i) * TS + n] = (bf16)(v > 0.f ? v : 0.f);
        }
    }
  }
  __syncthreads();  // barrier 1: feat + zsum ready

  // ---- W1c GEMM (K=128) + fused z-add + relu, in-place into xz (wave w: cols w*64..+63)
  {
    f32x4 acc1[4][4] = {};
#pragma unroll
    for (int kc = 0; kc < 4; ++kc) {
      bf16x8 afr[4];
#pragma unroll
      for (int g = 0; g < 4; ++g)
        afr[g] = *(const bf16x8*)&feat[(g * 16 + col) * TS + kc * 32 + quad * 8];
#pragma unroll
      for (int nt = 0; nt < 4; ++nt) {
        const int n = w * 64 + nt * 16 + col;
        bf16x8 b = *(const bf16x8*)(W1c + (size_t)n * 384 + kc * 32 + quad * 8);
#pragma unroll
        for (int g = 0; g < 4; ++g) acc1[g][nt] = mfma16(afr[g], b, acc1[g][nt]);
      }
    }
#pragma unroll
    for (int nt = 0; nt < 4; ++nt) {
      const int n = w * 64 + nt * 16 + col;
      const float b1 = B1[n];
#pragma unroll
      for (int g = 0; g < 4; ++g)
#pragma unroll
        for (int i = 0; i < 4; ++i) {
          const int m = g * 16 + quad * 4 + i;
          float v = acc1[g][nt][i] + b1 + (float)xz[m * XS + n];
          xz[m * XS + n] = (bf16)(v > 0.f ? v : 0.f);
        }
    }
  }
  __syncthreads();  // barrier 2: xz = relu(z) ready

  // ---- layer2 (K=256) (wave w: cols w*32..+31)
  f32x4 acc2[4][2] = {};
#pragma unroll
  for (int kc = 0; kc < 8; ++kc) {
    bf16x8 afr[4];
#pragma unroll
    for (int g = 0; g < 4; ++g)
      afr[g] = *(const bf16x8*)&xz[(g * 16 + col) * XS + kc * 32 + quad * 8];
#pragma unroll
    for (int nt = 0; nt < 2; ++nt) {
      const int n = w * 32 + nt * 16 + col;
      bf16x8 b = *(const bf16x8*)(W2t + (size_t)n * 256 + kc * 32 + quad * 8);
#pragma unroll
      for (int g = 0; g < 4; ++g) acc2[g][nt] = mfma16(afr[g], b, acc2[g][nt]);
    }
  }
  __syncthreads();  // barrier 3: xz reads done; sred may overwrite

  // ---- sred write (wave-private cols) + segmented reduce + atomics
#pragma unroll
  for (int nt = 0; nt < 2; ++nt) {
    const int n = w * 32 + nt * 16 + col;
    const float b2 = B2[n];
#pragma unroll
    for (int g = 0; g < 4; ++g)
#pragma unroll
      for (int i = 0; i < 4; ++i) {
        float v = acc2[g][nt][i] + b2;
        sred[(g * 16 + quad * 4 + i) * SRS + n] = v > 0.f ? v : 0.f;
      }
  }
  {
    const int c = w * 32 + (lane >> 1);
    const int rlo = (lane & 1) * 32;
    float run = 0.f;
    int cur = s_own[rlo];
    for (int r = rlo; r < rlo + 32; ++r) {
      int k = s_own[r];
      if (k != cur) {
        if (cur >= 0)
          __hip_atomic_fetch_add(&acc[(size_t)cur * D_DIM + c], run,
                                 __ATOMIC_RELAXED, __HIP_MEMORY_SCOPE_AGENT);
        run = 0.f;
        cur = k;
      }
      run += sred[r * SRS + c];
    }
    if (cur >= 0)
      __hip_atomic_fetch_add(&acc[(size_t)cur * D_DIM + c], run,
                             __ATOMIC_RELAXED, __HIP_MEMORY_SCOPE_AGENT);
  }
}

// ---------------- per-hop node kernel: MLP_A + residual (h f32 in/out) ----------------

__global__ __launch_bounds__(256, 2) void node_a_kernel(
    const float* __restrict__ h, const float* __restrict__ accp, const float* __restrict__ accc,
    const float* __restrict__ invp, const float* __restrict__ invc,
    const float* __restrict__ pmask, const float* __restrict__ cmask,
    const float* __restrict__ stok, const float* __restrict__ etok,
    const bf16* __restrict__ W1t, const float* __restrict__ B1,
    const bf16* __restrict__ W2t, const float* __restrict__ B2,
    float* __restrict__ hout, int N) {
  __shared__ __attribute__((aligned(16))) bf16 x[NB * AS];  // [h | s_p | s_c]
  __shared__ __attribute__((aligned(16))) bf16 x2[NB * XS];
  const int t = threadIdx.x;
  const int r0 = blockIdx.x * NB;
  {
    const int r = t >> 3, c0 = (t & 7) * 16;
    int g = r0 + r; if (g >= N) g = N - 1;
    stage16(h + (size_t)g * D_DIM + c0, &x[r * AS + c0]);
  }
  {
    const int j = t;  // cols 128..383
    for (int r = 0; r < NB; ++r) {
      int g = r0 + r; if (g >= N) g = N - 1;
      float v;
      if (j < 128)
        v = accp[(size_t)g * D_DIM + j] * invp[g] + pmask[g] * stok[j];
      else {
        int jj = j - 128;
        v = accc[(size_t)g * D_DIM + jj] * invc[g] + cmask[g] * etok[jj];
      }
      x[r * AS + 128 + j] = (bf16)v;
    }
  }
  __syncthreads();
  const int lane = t & 63, w = t >> 6, col = lane & 15, quad = lane >> 4;
  mlp_layer1<3>(x, x + 128, x + 256, AS, W1t, B1, x2, lane, w);
  __syncthreads();
  f32x4 acc2[2][2] = {};
  mlp_layer2(x2, W2t, lane, w, acc2);
#pragma unroll
  for (int nt = 0; nt < 2; ++nt) {
    const int n = w * 32 + nt * 16 + col;
    const float b2 = B2[n];
#pragma unroll
    for (int mt = 0; mt < 2; ++mt)
#pragma unroll
      for (int i = 0; i < 4; ++i) {
        int m = mt * 16 + quad * 4 + i;
        int g = r0 + m;
        if (g < N) {
          float mlpv = acc2[mt][nt][i] + b2;
          mlpv = mlpv > 0.f ? mlpv : 0.f;
          float v = h[(size_t)g * D_DIM + n] + mlpv;  // exact f32 residual
          hout[(size_t)g * D_DIM + n] = v > 0.f ? v : 0.f;
        }
      }
  }
}

// ---------------- host launch ----------------

extern "C" void kernel_launch(void* const* d_in, const int* in_sizes, int n_in,
                              void* d_out, int out_size, void* d_ws, size_t ws_size,
                              hipStream_t stream) {
  const float* batch_token = (const float*)d_in[0];
  const int* epn = (const int*)d_in[1];
  const int* ecn = (const int*)d_in[2];
  const float* epi = (const float*)d_in[3];
  const float* eci = (const float*)d_in[4];
  const float* pmask = (const float*)d_in[5];
  const float* cmask = (const float*)d_in[6];
  const float* stok = (const float*)d_in[7];
  const float* etok = (const float*)d_in[8];
  const float *Vw1 = (const float*)d_in[9], *Vb1 = (const float*)d_in[10],
              *Vw2 = (const float*)d_in[11], *Vb2 = (const float*)d_in[12];
  const float *Ew1 = (const float*)d_in[13], *Eb1 = (const float*)d_in[14],
              *Ew2 = (const float*)d_in[15], *Eb2 = (const float*)d_in[16];
  const float *Pw1 = (const float*)d_in[17], *Pb1 = (const float*)d_in[18],
              *Pw2 = (const float*)d_in[19], *Pb2 = (const float*)d_in[20];
  const float *Cw1 = (const float*)d_in[21], *Cb1 = (const float*)d_in[22],
              *Cw2 = (const float*)d_in[23], *Cb2 = (const float*)d_in[24];
  const float *Aw1 = (const float*)d_in[25], *Ab1 = (const float*)d_in[26],
              *Aw2 = (const float*)d_in[27], *Ab2 = (const float*)d_in[28];
  const int N = in_sizes[5];  // p_mask length
  const int E = in_sizes[1];  // edge_p_node length

  char* ws = (char*)d_ws;
  size_t off = 0;
  auto alloc = [&](size_t bytes) {
    size_t o = off;
    off += (bytes + 511) & ~(size_t)511;
    return o;
  };
  float* accp = (float*)(ws + alloc((size_t)N * D_DIM * 4));
  float* accc = (float*)(ws + alloc((size_t)N * D_DIM * 4));
  bf16* Zbuf = (bf16*)(ws + alloc((size_t)4 * N * 256 * 2));  // ZO_P, ZW_P, ZO_C, ZW_C
  float* invp = (float*)(ws + alloc((size_t)N * 4));
  float* invc = (float*)(ws + alloc((size_t)N * 4));
  int* cntp = (int*)(ws + alloc((size_t)N * 4));
  int* cntc = (int*)(ws + alloc((size_t)N * 4));
  int* offp = (int*)(ws + alloc((size_t)N * 4));
  int* offc = (int*)(ws + alloc((size_t)N * 4));
  int* curp = (int*)(ws + alloc((size_t)N * 4));
  int* curc = (int*)(ws + alloc((size_t)N * 4));
  int* sortp = (int*)(ws + alloc((size_t)E * 4));
  int* sortc = (int*)(ws + alloc((size_t)E * 4));
  bf16* Vw1t = (bf16*)(ws + alloc(128 * 256 * 2));
  bf16* Pw1t = (bf16*)(ws + alloc(384 * 256 * 2));
  bf16* Cw1t = (bf16*)(ws + alloc(384 * 256 * 2));
  bf16* Aw1t = (bf16*)(ws + alloc(384 * 256 * 2));
  bf16* Vw2t = (bf16*)(ws + alloc(256 * 128 * 2));
  bf16* Ew2t = (bf16*)(ws + alloc(256 * 128 * 2));
  bf16* Pw2t = (bf16*)(ws + alloc(256 * 128 * 2));
  bf16* Cw2t = (bf16*)(ws + alloc(256 * 128 * 2));
  bf16* Aw2t = (bf16*)(ws + alloc(256 * 128 * 2));
  float* hbuf = (float*)d_out;  // h f32 lives in d_out across hops
  (void)ws_size; (void)n_in; (void)out_size;

  const dim3 blk(256);
  // weight transposes (f32 -> bf16): out[n*K+k] = in[k*N+n]
  transpose_kernel<<<dim3(1, 256), blk, 0, stream>>>(Vw1, Vw1t, 128, 256);
  transpose_kernel<<<dim3(2, 256), blk, 0, stream>>>(Pw1, Pw1t, 384, 256);
  transpose_kernel<<<dim3(2, 256), blk, 0, stream>>>(Cw1, Cw1t, 384, 256);
  transpose_kernel<<<dim3(2, 256), blk, 0, stream>>>(Aw1, Aw1t, 384, 256);
  transpose_kernel<<<dim3(1, 128), blk, 0, stream>>>(Vw2, Vw2t, 256, 128);
  transpose_kernel<<<dim3(1, 128), blk, 0, stream>>>(Ew2, Ew2t, 256, 128);
  transpose_kernel<<<dim3(1, 128), blk, 0, stream>>>(Pw2, Pw2t, 256, 128);
  transpose_kernel<<<dim3(1, 128), blk, 0, stream>>>(Cw2, Cw2t, 256, 128);
  transpose_kernel<<<dim3(1, 128), blk, 0, stream>>>(Aw2, Aw2t, 256, 128);

  // degree counts -> reciprocals; counting sort (hop-invariant)
  const size_t cntbytes = (size_t)((char*)(cntc + N) - (char*)cntp);
  hipMemsetAsync(cntp, 0, cntbytes, stream);
  count_kernel<<<dim3((E + 255) / 256), blk, 0, stream>>>(epn, ecn, cntp, cntc, E, N);
  inv_kernel<<<dim3((N + 255) / 256), blk, 0, stream>>>(cntp, cntc, invp, invc, N);
  scan_kernel<<<dim3(1), dim3(1024), 0, stream>>>(cntp, offp, N);
  scan_kernel<<<dim3(1), dim3(1024), 0, stream>>>(cntc, offc, N);
  const size_t curbytes = (size_t)((char*)(curc + N) - (char*)curp);
  hipMemsetAsync(curp, 0, curbytes, stream);
  scatter_kernel<<<dim3((E + 255) / 256), blk, 0, stream>>>(epn, ecn, offp, offc,
                                                            curp, curc, sortp, sortc, E, N);

  const int nblocks = (N + NB - 1) / NB;
  const int eblocks = (E + EB - 1) / EB;

  // h = MLP_V(batch_token)  (f32 into d_out)
  node_v_kernel<<<dim3(nblocks), blk, 0, stream>>>(batch_token, Vw1t, Vb1, Vw2t, Vb2, hbuf, N);

  const size_t accbytes = (size_t)((char*)(accc + (size_t)N * D_DIM) - (char*)accp);
  for (int hop = 0; hop < 3; ++hop) {
    zgemm_kernel<<<dim3(nblocks), blk, 0, stream>>>(hbuf, Pw1t, Cw1t, Zbuf, N);
    hipMemsetAsync(accp, 0, accbytes, stream);
    edge_side_kernel<<<dim3(eblocks, 2), blk, 0, stream>>>(
        Zbuf, epi, eci, epn, ecn, sortp, sortc, Ew1, Eb1, Ew2t, Eb2,
        Pw1t, Pb1, Pw2t, Pb2, Cw1t, Cb1, Cw2t, Cb2, accp, accc, E, N);
    node_a_kernel<<<dim3(nblocks), blk, 0, stream>>>(
        hbuf, accp, accc, invp, invc, pmask, cmask, stok, etok,
        Aw1t, Ab1, Aw2t, Ab2, hbuf, N);
  }
}